// Round 1
// baseline (1702.208 us; speedup 1.0000x reference)
//
#include <hip/hip_runtime.h>

// NodeGNN: h = lrelu(lrelu(x@W1+b1)@W2+b2); 2x GCNConv(16->16) over E=6.4M edges
// + self loops with symmetric norm; out = sum(h@pw+pb, -1). Returns (out[N], h[N,16]).
//
// Strategy: fused fp32 MLP (register-tiled, LDS-staged), then build unordered CSR
// (count -> wave-scan alloc -> place) once and run both convs as gathers (no fp32
// atomics). Self-loop folded into the gather init term.

#define NEG 0.01f

__device__ __forceinline__ float lrelu(float v) { return v >= 0.0f ? v : NEG * v; }

// ---------------------------------------------------------------------------
// K1: fused MLP. Block = 256 threads, 64 nodes/block.
// Stage A: h1[64][256] = lrelu(x_tile @ W1 + b1), 8x8 register tile/thread.
// Stage B: h[64][16]   = lrelu(h1 @ W2 + b2) via LDS (bank-rotated reads).
// Also zero-inits cnt[] and the CSR allocation counter for this call.
// ---------------------------------------------------------------------------
__global__ __launch_bounds__(256, 2) void mlp_kernel(
    const float* __restrict__ x, const float* __restrict__ W1, const float* __restrict__ b1,
    const float* __restrict__ W2, const float* __restrict__ b2,
    float* __restrict__ h, int* __restrict__ cnt, unsigned int* __restrict__ alloc_ctr, int N)
{
    __shared__ union {
        struct { float xs[64][128]; float ws[32][256]; } a;  // 32KB + 32KB
        float h1s[64][256];                                  // 64KB (exact union)
    } sm;

    const int tid = threadIdx.x;
    const int n0  = blockIdx.x * 64;

    if (tid < 64 && (n0 + tid) < N) cnt[n0 + tid] = 0;       // ws is poisoned each call
    if (blockIdx.x == 0 && tid == 0) *alloc_ctr = 0u;

    // x tile -> LDS (contiguous float4, coalesced)
    {
        const float4* xg  = (const float4*)(x + (size_t)n0 * 128);
        float4*       xls = (float4*)sm.a.xs;
#pragma unroll
        for (int i = 0; i < 8; ++i) { int f = tid + 256 * i; xls[f] = xg[f]; }
    }

    const int tx = tid & 31, ty = tid >> 5;
    const int c0 = tx * 8,  m0 = ty * 8;   // 8 cols x 8 nodes per thread

    float acc[8][8];
#pragma unroll
    for (int i = 0; i < 8; ++i)
#pragma unroll
        for (int j = 0; j < 8; ++j) acc[i][j] = 0.0f;

    for (int kc = 0; kc < 128; kc += 32) {
        __syncthreads();
        {   // W1 chunk rows [kc, kc+32) -> LDS
            const float4* wg  = (const float4*)(W1 + (size_t)kc * 256);
            float4*       wls = (float4*)sm.a.ws;
#pragma unroll
            for (int i = 0; i < 8; ++i) { int f = tid + 256 * i; wls[f] = wg[f]; }
        }
        __syncthreads();

#pragma unroll
        for (int kk = 0; kk < 32; kk += 4) {
            float4 xa[8];
#pragma unroll
            for (int m = 0; m < 8; ++m) xa[m] = *(const float4*)&sm.a.xs[m0 + m][kc + kk];
            float4 wlo[4], whi[4];
#pragma unroll
            for (int j = 0; j < 4; ++j) {
                wlo[j] = *(const float4*)&sm.a.ws[kk + j][c0];
                whi[j] = *(const float4*)&sm.a.ws[kk + j][c0 + 4];
            }
#pragma unroll
            for (int m = 0; m < 8; ++m) {
                float xv[4] = {xa[m].x, xa[m].y, xa[m].z, xa[m].w};
#pragma unroll
                for (int j = 0; j < 4; ++j) {
                    acc[m][0] += xv[j] * wlo[j].x; acc[m][1] += xv[j] * wlo[j].y;
                    acc[m][2] += xv[j] * wlo[j].z; acc[m][3] += xv[j] * wlo[j].w;
                    acc[m][4] += xv[j] * whi[j].x; acc[m][5] += xv[j] * whi[j].y;
                    acc[m][6] += xv[j] * whi[j].z; acc[m][7] += xv[j] * whi[j].w;
                }
            }
        }
    }

    // epilogue A: + b1, leaky, -> h1s (reuses the xs/ws LDS)
    float4 b0 = *(const float4*)&b1[c0];
    float4 b4 = *(const float4*)&b1[c0 + 4];
    __syncthreads();
#pragma unroll
    for (int m = 0; m < 8; ++m) {
        float4 lo, hi;
        lo.x = lrelu(acc[m][0] + b0.x); lo.y = lrelu(acc[m][1] + b0.y);
        lo.z = lrelu(acc[m][2] + b0.z); lo.w = lrelu(acc[m][3] + b0.w);
        hi.x = lrelu(acc[m][4] + b4.x); hi.y = lrelu(acc[m][5] + b4.y);
        hi.z = lrelu(acc[m][6] + b4.z); hi.w = lrelu(acc[m][7] + b4.w);
        *(float4*)&sm.h1s[m0 + m][c0]     = lo;
        *(float4*)&sm.h1s[m0 + m][c0 + 4] = hi;
    }
    __syncthreads();

    // stage B: node m = tid>>2, cols cg..cg+3. k-order rotated by m*4 so the 16
    // distinct LDS rows in a wave land on 8 bank positions (2-way = free).
    const int m  = tid >> 2;
    const int cg = (tid & 3) * 4;
    const int rot = (m * 4) & 255;
    float f0 = 0.f, f1 = 0.f, f2 = 0.f, f3 = 0.f;
#pragma unroll 4
    for (int kk = 0; kk < 256; kk += 4) {
        int k = (kk + rot) & 255;
        float4 hv = *(const float4*)&sm.h1s[m][k];
        float4 w0 = *(const float4*)&W2[(k + 0) * 16 + cg];
        float4 w1 = *(const float4*)&W2[(k + 1) * 16 + cg];
        float4 w2 = *(const float4*)&W2[(k + 2) * 16 + cg];
        float4 w3 = *(const float4*)&W2[(k + 3) * 16 + cg];
        f0 += hv.x * w0.x + hv.y * w1.x + hv.z * w2.x + hv.w * w3.x;
        f1 += hv.x * w0.y + hv.y * w1.y + hv.z * w2.y + hv.w * w3.y;
        f2 += hv.x * w0.z + hv.y * w1.z + hv.z * w2.z + hv.w * w3.z;
        f3 += hv.x * w0.w + hv.y * w1.w + hv.z * w2.w + hv.w * w3.w;
    }
    float4 ob = *(const float4*)&b2[cg];
    float4 hv;
    hv.x = lrelu(f0 + ob.x); hv.y = lrelu(f1 + ob.y);
    hv.z = lrelu(f2 + ob.z); hv.w = lrelu(f3 + ob.w);
    *(float4*)&h[(size_t)(n0 + m) * 16 + cg] = hv;
}

// ---------------------------------------------------------------------------
// K2: in-degree count (E int atomics)
// ---------------------------------------------------------------------------
__global__ void count_kernel(const int* __restrict__ eidx, int* __restrict__ cnt, int E, int N)
{
    int e = blockIdx.x * 256 + threadIdx.x;
    if (e >= E) return;
    int d = eidx[E + e];               // edge_index[1][e]
    if ((unsigned)d < (unsigned)N) atomicAdd(&cnt[d], 1);
}

// ---------------------------------------------------------------------------
// K3: CSR slot allocation (wave scan + 1 atomic/wave; order irrelevant),
//     plus dinv = 1/sqrt(deg+1) (self loop included).
// ---------------------------------------------------------------------------
__global__ void alloc_kernel(const int* __restrict__ cnt, int* __restrict__ row_start,
                             int* __restrict__ cursor, float* __restrict__ dinv,
                             unsigned int* __restrict__ ctr, int N)
{
    int i    = blockIdx.x * 256 + threadIdx.x;
    int lane = threadIdx.x & 63;
    int ci   = (i < N) ? cnt[i] : 0;

    int scan = ci;                     // inclusive wave scan
#pragma unroll
    for (int off = 1; off < 64; off <<= 1) {
        int u = __shfl_up(scan, off);
        if (lane >= off) scan += u;
    }
    int total = __shfl(scan, 63);
    int base  = 0;
    if (lane == 63) base = (int)atomicAdd(ctr, (unsigned int)total);
    base = __shfl(base, 63);

    if (i < N) {
        int s = base + (scan - ci);    // exclusive offset within wave's range
        row_start[i] = s;
        cursor[i]    = s;
        dinv[i]      = 1.0f / sqrtf((float)(ci + 1));
    }
}

// ---------------------------------------------------------------------------
// K4: hw = (optionally lrelu(in + bias_prev)) @ W[16x16]. Thread per node.
// ---------------------------------------------------------------------------
__global__ void hw_kernel(const float* __restrict__ in, const float* __restrict__ W,
                          const float* __restrict__ bias, float* __restrict__ out,
                          int N, int apply)
{
    int i = blockIdx.x * 256 + threadIdx.x;
    if (i >= N) return;
    const float4* ir = (const float4*)(in + (size_t)i * 16);
    float4 r0 = ir[0], r1 = ir[1], r2 = ir[2], r3 = ir[3];
    float v[16] = {r0.x, r0.y, r0.z, r0.w, r1.x, r1.y, r1.z, r1.w,
                   r2.x, r2.y, r2.z, r2.w, r3.x, r3.y, r3.z, r3.w};
    if (apply) {
#pragma unroll
        for (int c = 0; c < 16; ++c) v[c] = lrelu(v[c] + bias[c]);
    }
    float o[16];
#pragma unroll
    for (int c = 0; c < 16; ++c) o[c] = 0.0f;
#pragma unroll
    for (int k = 0; k < 16; ++k) {
        float vk = v[k];
#pragma unroll
        for (int c = 0; c < 16; ++c) o[c] += vk * W[k * 16 + c];  // W uniform -> s_loads
    }
    float4* orow = (float4*)(out + (size_t)i * 16);
    orow[0] = make_float4(o[0],  o[1],  o[2],  o[3]);
    orow[1] = make_float4(o[4],  o[5],  o[6],  o[7]);
    orow[2] = make_float4(o[8],  o[9],  o[10], o[11]);
    orow[3] = make_float4(o[12], o[13], o[14], o[15]);
}

// ---------------------------------------------------------------------------
// K5: place edges into CSR slots (E int atomics)
// ---------------------------------------------------------------------------
__global__ void place_kernel(const int* __restrict__ eidx, int* __restrict__ cursor,
                             int* __restrict__ csr, int E, int N)
{
    int e = blockIdx.x * 256 + threadIdx.x;
    if (e >= E) return;
    int s = eidx[e];
    int d = eidx[E + e];
    if ((unsigned)s >= (unsigned)N || (unsigned)d >= (unsigned)N) return;
    int pos = atomicAdd(&cursor[d], 1);
    csr[pos] = s;
}

// ---------------------------------------------------------------------------
// K6: gather conv. 16 lanes per node, lane c owns feature c.
// agg[i] = dinv_i * (hw_i*dinv_i + sum_src hw_src*dinv_src)   (self loop folded)
// ---------------------------------------------------------------------------
__global__ __launch_bounds__(256) void gather_kernel(
    const float* __restrict__ hw, const float* __restrict__ dinv,
    const int* __restrict__ csr, const int* __restrict__ row_start,
    const int* __restrict__ cnt, float* __restrict__ agg, int N)
{
    int t    = blockIdx.x * 256 + threadIdx.x;
    int node = t >> 4;
    int c    = t & 15;
    if (node >= N) return;

    int   s0 = row_start[node];
    int   n  = cnt[node];
    float di = dinv[node];
    float acc = hw[node * 16 + c] * di;

    int j = 0;
    for (; j + 4 <= n; j += 4) {
        int sa = csr[s0 + j + 0]; int sb = csr[s0 + j + 1];
        int sc = csr[s0 + j + 2]; int sd = csr[s0 + j + 3];
        sa = ((unsigned)sa < (unsigned)N) ? sa : 0;
        sb = ((unsigned)sb < (unsigned)N) ? sb : 0;
        sc = ((unsigned)sc < (unsigned)N) ? sc : 0;
        sd = ((unsigned)sd < (unsigned)N) ? sd : 0;
        float ga = hw[sa * 16 + c], gb = hw[sb * 16 + c];
        float gc = hw[sc * 16 + c], gd = hw[sd * 16 + c];
        float da = dinv[sa], db = dinv[sb], dc = dinv[sc], dd = dinv[sd];
        acc += ga * da; acc += gb * db; acc += gc * dc; acc += gd * dd;
    }
    for (; j < n; ++j) {
        int s = csr[s0 + j];
        s = ((unsigned)s < (unsigned)N) ? s : 0;
        acc += hw[s * 16 + c] * dinv[s];
    }
    agg[node * 16 + c] = acc * di;
}

// ---------------------------------------------------------------------------
// K7: final head. h = lrelu(agg + cb1); out = h . (pw[:,0]+pw[:,1]) + pb0+pb1
// d_out = [ out[N] | h[N*16] ]
// ---------------------------------------------------------------------------
__global__ void final_kernel(const float* __restrict__ agg, const float* __restrict__ cb1,
                             const float* __restrict__ pw, const float* __restrict__ pb,
                             float* __restrict__ out, float* __restrict__ hout, int N)
{
    int i = blockIdx.x * 256 + threadIdx.x;
    if (i >= N) return;
    const float4* ar = (const float4*)(agg + (size_t)i * 16);
    float4 r0 = ar[0], r1 = ar[1], r2 = ar[2], r3 = ar[3];
    float v[16] = {r0.x, r0.y, r0.z, r0.w, r1.x, r1.y, r1.z, r1.w,
                   r2.x, r2.y, r2.z, r2.w, r3.x, r3.y, r3.z, r3.w};
    float s = pb[0] + pb[1];
#pragma unroll
    for (int c = 0; c < 16; ++c) {
        v[c] = lrelu(v[c] + cb1[c]);
        s += v[c] * (pw[c * 2] + pw[c * 2 + 1]);
    }
    out[i] = s;
    float4* hr = (float4*)(hout + (size_t)i * 16);
    hr[0] = make_float4(v[0],  v[1],  v[2],  v[3]);
    hr[1] = make_float4(v[4],  v[5],  v[6],  v[7]);
    hr[2] = make_float4(v[8],  v[9],  v[10], v[11]);
    hr[3] = make_float4(v[12], v[13], v[14], v[15]);
}

// ---------------------------------------------------------------------------
extern "C" void kernel_launch(void* const* d_in, const int* in_sizes, int n_in,
                              void* d_out, int out_size, void* d_ws, size_t ws_size,
                              hipStream_t stream)
{
    const float* x   = (const float*)d_in[0];
    const float* W1  = (const float*)d_in[1];
    const float* b1  = (const float*)d_in[2];
    const float* W2  = (const float*)d_in[3];
    const float* b2  = (const float*)d_in[4];
    const float* cw0 = (const float*)d_in[5];
    const float* cb0 = (const float*)d_in[6];
    const float* cw1 = (const float*)d_in[7];
    const float* cb1 = (const float*)d_in[8];
    const float* pw  = (const float*)d_in[9];
    const float* pb  = (const float*)d_in[10];
    const int*   eidx = (const int*)d_in[11];

    const int N = in_sizes[0] / 128;
    const int E = in_sizes[11] / 2;

    // workspace carve-out (~67 MB)
    char* w = (char*)d_ws;
    float* h        = (float*)w; w += (size_t)N * 16 * 4;
    float* hw       = (float*)w; w += (size_t)N * 16 * 4;
    float* agg      = (float*)w; w += (size_t)N * 16 * 4;
    float* dinv     = (float*)w; w += (size_t)N * 4;
    int*   cnt      = (int*)w;   w += (size_t)N * 4;
    int*   row_st   = (int*)w;   w += (size_t)N * 4;
    int*   cursor   = (int*)w;   w += (size_t)N * 4;
    int*   csr      = (int*)w;   w += (size_t)E * 4;
    unsigned int* ctr = (unsigned int*)w;

    float* out  = (float*)d_out;
    float* hout = out + N;

    const int nb_n = (N + 255) / 256;
    const int nb_e = (E + 255) / 256;
    const int nb_g = (N * 16 + 255) / 256;

    mlp_kernel<<<N / 64, 256, 0, stream>>>(x, W1, b1, W2, b2, h, cnt, ctr, N);
    count_kernel<<<nb_e, 256, 0, stream>>>(eidx, cnt, E, N);
    alloc_kernel<<<nb_n, 256, 0, stream>>>(cnt, row_st, cursor, dinv, ctr, N);
    hw_kernel<<<nb_n, 256, 0, stream>>>(h, cw0, nullptr, hw, N, 0);
    place_kernel<<<nb_e, 256, 0, stream>>>(eidx, cursor, csr, E, N);
    gather_kernel<<<nb_g, 256, 0, stream>>>(hw, dinv, csr, row_st, cnt, agg, N);
    hw_kernel<<<nb_n, 256, 0, stream>>>(agg, cw1, cb0, hw, N, 1);
    gather_kernel<<<nb_g, 256, 0, stream>>>(hw, dinv, csr, row_st, cnt, agg, N);
    final_kernel<<<nb_n, 256, 0, stream>>>(agg, cb1, pw, pb, out, hout, N);
}

// Round 2
// 1142.242 us; speedup vs baseline: 1.4902x; 1.4902x over previous
//
#include <hip/hip_runtime.h>

// NodeGNN: h = lrelu(lrelu(x@W1+b1)@W2+b2); 2x GCNConv(16->16) over E=6.4M edges
// + self loops with symmetric norm; out = sum(h@pw+pb, -1). Returns (out[N], h[N,16]).
//
// R2: replaced atomic scatter CSR-place (392MB amplified writes, 585us) with a
// two-level bucketed build: partition edges into 512-node buckets with per-block
// LDS histograms + one global atomic per (block,bucket) and contiguous run writes;
// then per-bucket LDS counting sort confines csr scatter to a 64KB L2-held region.
// count_kernel/alloc_kernel folded into build_csr (cnt/row_start/dinv from LDS scan).

#define NEG 0.01f
#define SHIFT 9                 // 512 nodes per bucket
#define BNODES (1 << SHIFT)
#define BMAX 512                // max buckets (N <= 262144)

__device__ __forceinline__ float lrelu(float v) { return v >= 0.0f ? v : NEG * v; }

// ---------------------------------------------------------------------------
// K1: fused MLP. Block = 256 threads, 64 nodes/block.
// ---------------------------------------------------------------------------
__global__ __launch_bounds__(256, 2) void mlp_kernel(
    const float* __restrict__ x, const float* __restrict__ W1, const float* __restrict__ b1,
    const float* __restrict__ W2, const float* __restrict__ b2,
    float* __restrict__ h, int N)
{
    __shared__ union {
        struct { float xs[64][128]; float ws[32][256]; } a;  // 32KB + 32KB
        float h1s[64][256];                                  // 64KB (exact union)
    } sm;

    const int tid = threadIdx.x;
    const int n0  = blockIdx.x * 64;

    {
        const float4* xg  = (const float4*)(x + (size_t)n0 * 128);
        float4*       xls = (float4*)sm.a.xs;
#pragma unroll
        for (int i = 0; i < 8; ++i) { int f = tid + 256 * i; xls[f] = xg[f]; }
    }

    const int tx = tid & 31, ty = tid >> 5;
    const int c0 = tx * 8,  m0 = ty * 8;

    float acc[8][8];
#pragma unroll
    for (int i = 0; i < 8; ++i)
#pragma unroll
        for (int j = 0; j < 8; ++j) acc[i][j] = 0.0f;

    for (int kc = 0; kc < 128; kc += 32) {
        __syncthreads();
        {
            const float4* wg  = (const float4*)(W1 + (size_t)kc * 256);
            float4*       wls = (float4*)sm.a.ws;
#pragma unroll
            for (int i = 0; i < 8; ++i) { int f = tid + 256 * i; wls[f] = wg[f]; }
        }
        __syncthreads();

#pragma unroll
        for (int kk = 0; kk < 32; kk += 4) {
            float4 xa[8];
#pragma unroll
            for (int m = 0; m < 8; ++m) xa[m] = *(const float4*)&sm.a.xs[m0 + m][kc + kk];
            float4 wlo[4], whi[4];
#pragma unroll
            for (int j = 0; j < 4; ++j) {
                wlo[j] = *(const float4*)&sm.a.ws[kk + j][c0];
                whi[j] = *(const float4*)&sm.a.ws[kk + j][c0 + 4];
            }
#pragma unroll
            for (int m = 0; m < 8; ++m) {
                float xv[4] = {xa[m].x, xa[m].y, xa[m].z, xa[m].w};
#pragma unroll
                for (int j = 0; j < 4; ++j) {
                    acc[m][0] += xv[j] * wlo[j].x; acc[m][1] += xv[j] * wlo[j].y;
                    acc[m][2] += xv[j] * wlo[j].z; acc[m][3] += xv[j] * wlo[j].w;
                    acc[m][4] += xv[j] * whi[j].x; acc[m][5] += xv[j] * whi[j].y;
                    acc[m][6] += xv[j] * whi[j].z; acc[m][7] += xv[j] * whi[j].w;
                }
            }
        }
    }

    float4 b0 = *(const float4*)&b1[c0];
    float4 b4 = *(const float4*)&b1[c0 + 4];
    __syncthreads();
#pragma unroll
    for (int m = 0; m < 8; ++m) {
        float4 lo, hi;
        lo.x = lrelu(acc[m][0] + b0.x); lo.y = lrelu(acc[m][1] + b0.y);
        lo.z = lrelu(acc[m][2] + b0.z); lo.w = lrelu(acc[m][3] + b0.w);
        hi.x = lrelu(acc[m][4] + b4.x); hi.y = lrelu(acc[m][5] + b4.y);
        hi.z = lrelu(acc[m][6] + b4.z); hi.w = lrelu(acc[m][7] + b4.w);
        *(float4*)&sm.h1s[m0 + m][c0]     = lo;
        *(float4*)&sm.h1s[m0 + m][c0 + 4] = hi;
    }
    __syncthreads();

    const int m  = tid >> 2;
    const int cg = (tid & 3) * 4;
    const int rot = (m * 4) & 255;
    float f0 = 0.f, f1 = 0.f, f2 = 0.f, f3 = 0.f;
#pragma unroll 4
    for (int kk = 0; kk < 256; kk += 4) {
        int k = (kk + rot) & 255;
        float4 hv = *(const float4*)&sm.h1s[m][k];
        float4 w0 = *(const float4*)&W2[(k + 0) * 16 + cg];
        float4 w1 = *(const float4*)&W2[(k + 1) * 16 + cg];
        float4 w2 = *(const float4*)&W2[(k + 2) * 16 + cg];
        float4 w3 = *(const float4*)&W2[(k + 3) * 16 + cg];
        f0 += hv.x * w0.x + hv.y * w1.x + hv.z * w2.x + hv.w * w3.x;
        f1 += hv.x * w0.y + hv.y * w1.y + hv.z * w2.y + hv.w * w3.y;
        f2 += hv.x * w0.z + hv.y * w1.z + hv.z * w2.z + hv.w * w3.z;
        f3 += hv.x * w0.w + hv.y * w1.w + hv.z * w2.w + hv.w * w3.w;
    }
    float4 ob = *(const float4*)&b2[cg];
    float4 hv;
    hv.x = lrelu(f0 + ob.x); hv.y = lrelu(f1 + ob.y);
    hv.z = lrelu(f2 + ob.z); hv.w = lrelu(f3 + ob.w);
    *(float4*)&h[(size_t)(n0 + m) * 16 + cg] = hv;
}

// ---------------------------------------------------------------------------
// K0: zero the global bucket counters (avoids memset-node in graph capture)
// ---------------------------------------------------------------------------
__global__ void zero_kernel(int* __restrict__ bcnt)
{
    bcnt[threadIdx.x] = 0;
}

// ---------------------------------------------------------------------------
// K2: per-bucket edge histogram (LDS-aggregated, one global atomic per block/bucket)
// ---------------------------------------------------------------------------
__global__ __launch_bounds__(256) void bucket_count(
    const int* __restrict__ eidx, int* __restrict__ bcnt, int E, int N, int B)
{
    __shared__ int hist[BMAX];
    const int t = threadIdx.x;
    for (int b = t; b < B; b += 256) hist[b] = 0;
    __syncthreads();

    const int stride = gridDim.x * 256;
    for (int e = blockIdx.x * 256 + t; e < E; e += stride) {
        int d = eidx[E + e];
        d = min(max(d, 0), N - 1);
        atomicAdd(&hist[d >> SHIFT], 1);
    }
    __syncthreads();
    for (int b = t; b < B; b += 256) {
        int c = hist[b];
        if (c) atomicAdd(&bcnt[b], c);
    }
}

// ---------------------------------------------------------------------------
// K3: single-block exclusive scan over bucket counts -> bbase[0..B], gcur=base
// ---------------------------------------------------------------------------
__global__ __launch_bounds__(512) void scan_kernel(
    const int* __restrict__ bcnt, int* __restrict__ bbase, int* __restrict__ gcur, int B)
{
    __shared__ int s[BMAX];
    const int t = threadIdx.x;        // 512 threads
    int c = (t < B) ? bcnt[t] : 0;
    s[t] = c;
    __syncthreads();
#pragma unroll
    for (int off = 1; off < BMAX; off <<= 1) {
        int v = s[t];
        int u = (t >= off) ? s[t - off] : 0;
        __syncthreads();
        s[t] = v + u;
        __syncthreads();
    }
    if (t < B) {
        int excl = s[t] - c;
        bbase[t] = excl;
        gcur[t]  = excl;
    }
    if (t == 0) bbase[B] = s[BMAX - 1];
}

// ---------------------------------------------------------------------------
// K4: partition edges into bucket runs. 8192 edges/block; LDS histogram;
// one global atomic per (block,bucket); packed write (src<<9 | dst&511).
// ---------------------------------------------------------------------------
__global__ __launch_bounds__(256) void partition_kernel(
    const int* __restrict__ eidx, int* __restrict__ gcur, int* __restrict__ pairs,
    int E, int N, int B)
{
    __shared__ int hist[BMAX];
    __shared__ int basec[BMAX];
    const int t  = threadIdx.x;
    const int e0 = blockIdx.x * 8192;
    const int elim = min(8192, E - e0);

    for (int b = t; b < B; b += 256) hist[b] = 0;
    __syncthreads();

    for (int i = t; i < elim; i += 256) {
        int d = eidx[E + e0 + i];
        d = min(max(d, 0), N - 1);
        atomicAdd(&hist[d >> SHIFT], 1);
    }
    __syncthreads();
    for (int b = t; b < B; b += 256) {
        int c = hist[b];
        basec[b] = c ? atomicAdd(&gcur[b], c) : 0;
    }
    __syncthreads();
    for (int i = t; i < elim; i += 256) {
        int s = eidx[e0 + i];
        int d = eidx[E + e0 + i];
        s = min(max(s, 0), N - 1);
        d = min(max(d, 0), N - 1);
        int b = d >> SHIFT;
        int p = atomicAdd(&basec[b], 1);
        pairs[p] = (s << SHIFT) | (d & (BNODES - 1));
    }
}

// ---------------------------------------------------------------------------
// K5: per-bucket counting sort -> csr, plus row_start/cnt/dinv (self loop in dinv).
// All per-node counters/cursors in LDS; csr writes stay in a ~64KB L2-held region.
// ---------------------------------------------------------------------------
__global__ __launch_bounds__(512) void build_csr(
    const int* __restrict__ pairs, const int* __restrict__ bbase,
    int* __restrict__ row_start, int* __restrict__ cnt_out, float* __restrict__ dinv,
    int* __restrict__ csr, int N)
{
    __shared__ int cnt[BNODES];
    __shared__ int off[BNODES];
    const int b = blockIdx.x, t = threadIdx.x;   // 512 threads
    const int node0 = b << SHIFT;
    const int lo = bbase[b], hi = bbase[b + 1];

    cnt[t] = 0;
    __syncthreads();
    for (int e = lo + t; e < hi; e += 512)
        atomicAdd(&cnt[pairs[e] & (BNODES - 1)], 1);
    __syncthreads();

    int c = cnt[t];
    off[t] = c;
    __syncthreads();
#pragma unroll
    for (int o = 1; o < BNODES; o <<= 1) {
        int v = off[t];
        int u = (t >= o) ? off[t - o] : 0;
        __syncthreads();
        off[t] = v + u;
        __syncthreads();
    }
    const int excl = off[t] - c;
    const int node = node0 + t;
    if (node < N) {
        row_start[node] = lo + excl;
        cnt_out[node]   = c;
        dinv[node]      = rsqrtf((float)(c + 1));
    }
    cnt[t] = lo + excl;              // reuse as cursor
    __syncthreads();
    for (int e = lo + t; e < hi; e += 512) {
        int v = pairs[e];
        int p = atomicAdd(&cnt[v & (BNODES - 1)], 1);
        csr[p] = v >> SHIFT;
    }
}

// ---------------------------------------------------------------------------
// K6: hw = (optionally lrelu(in + bias_prev)) @ W[16x16]. Thread per node.
// ---------------------------------------------------------------------------
__global__ void hw_kernel(const float* __restrict__ in, const float* __restrict__ W,
                          const float* __restrict__ bias, float* __restrict__ out,
                          int N, int apply)
{
    int i = blockIdx.x * 256 + threadIdx.x;
    if (i >= N) return;
    const float4* ir = (const float4*)(in + (size_t)i * 16);
    float4 r0 = ir[0], r1 = ir[1], r2 = ir[2], r3 = ir[3];
    float v[16] = {r0.x, r0.y, r0.z, r0.w, r1.x, r1.y, r1.z, r1.w,
                   r2.x, r2.y, r2.z, r2.w, r3.x, r3.y, r3.z, r3.w};
    if (apply) {
#pragma unroll
        for (int c = 0; c < 16; ++c) v[c] = lrelu(v[c] + bias[c]);
    }
    float o[16];
#pragma unroll
    for (int c = 0; c < 16; ++c) o[c] = 0.0f;
#pragma unroll
    for (int k = 0; k < 16; ++k) {
        float vk = v[k];
#pragma unroll
        for (int c = 0; c < 16; ++c) o[c] += vk * W[k * 16 + c];
    }
    float4* orow = (float4*)(out + (size_t)i * 16);
    orow[0] = make_float4(o[0],  o[1],  o[2],  o[3]);
    orow[1] = make_float4(o[4],  o[5],  o[6],  o[7]);
    orow[2] = make_float4(o[8],  o[9],  o[10], o[11]);
    orow[3] = make_float4(o[12], o[13], o[14], o[15]);
}

// ---------------------------------------------------------------------------
// K7: gather conv. 16 lanes per node, lane c owns feature c.
// agg[i] = dinv_i * (hw_i*dinv_i + sum_src hw_src*dinv_src)
// ---------------------------------------------------------------------------
__global__ __launch_bounds__(256) void gather_kernel(
    const float* __restrict__ hw, const float* __restrict__ dinv,
    const int* __restrict__ csr, const int* __restrict__ row_start,
    const int* __restrict__ cnt, float* __restrict__ agg, int N)
{
    int t    = blockIdx.x * 256 + threadIdx.x;
    int node = t >> 4;
    int c    = t & 15;
    if (node >= N) return;

    int   s0 = row_start[node];
    int   n  = cnt[node];
    float di = dinv[node];
    float acc = hw[node * 16 + c] * di;

    int j = 0;
    for (; j + 4 <= n; j += 4) {
        int sa = csr[s0 + j + 0]; int sb = csr[s0 + j + 1];
        int sc = csr[s0 + j + 2]; int sd = csr[s0 + j + 3];
        float ga = hw[sa * 16 + c], gb = hw[sb * 16 + c];
        float gc = hw[sc * 16 + c], gd = hw[sd * 16 + c];
        float da = dinv[sa], db = dinv[sb], dc = dinv[sc], dd = dinv[sd];
        acc += ga * da; acc += gb * db; acc += gc * dc; acc += gd * dd;
    }
    for (; j < n; ++j) {
        int s = csr[s0 + j];
        acc += hw[s * 16 + c] * dinv[s];
    }
    agg[node * 16 + c] = acc * di;
}

// ---------------------------------------------------------------------------
// K8: final head. h = lrelu(agg + cb1); out = h . (pw[:,0]+pw[:,1]) + pb0+pb1
// ---------------------------------------------------------------------------
__global__ void final_kernel(const float* __restrict__ agg, const float* __restrict__ cb1,
                             const float* __restrict__ pw, const float* __restrict__ pb,
                             float* __restrict__ out, float* __restrict__ hout, int N)
{
    int i = blockIdx.x * 256 + threadIdx.x;
    if (i >= N) return;
    const float4* ar = (const float4*)(agg + (size_t)i * 16);
    float4 r0 = ar[0], r1 = ar[1], r2 = ar[2], r3 = ar[3];
    float v[16] = {r0.x, r0.y, r0.z, r0.w, r1.x, r1.y, r1.z, r1.w,
                   r2.x, r2.y, r2.z, r2.w, r3.x, r3.y, r3.z, r3.w};
    float s = pb[0] + pb[1];
#pragma unroll
    for (int c = 0; c < 16; ++c) {
        v[c] = lrelu(v[c] + cb1[c]);
        s += v[c] * (pw[c * 2] + pw[c * 2 + 1]);
    }
    out[i] = s;
    float4* hr = (float4*)(hout + (size_t)i * 16);
    hr[0] = make_float4(v[0],  v[1],  v[2],  v[3]);
    hr[1] = make_float4(v[4],  v[5],  v[6],  v[7]);
    hr[2] = make_float4(v[8],  v[9],  v[10], v[11]);
    hr[3] = make_float4(v[12], v[13], v[14], v[15]);
}

// ---------------------------------------------------------------------------
extern "C" void kernel_launch(void* const* d_in, const int* in_sizes, int n_in,
                              void* d_out, int out_size, void* d_ws, size_t ws_size,
                              hipStream_t stream)
{
    const float* x   = (const float*)d_in[0];
    const float* W1  = (const float*)d_in[1];
    const float* b1  = (const float*)d_in[2];
    const float* W2  = (const float*)d_in[3];
    const float* b2  = (const float*)d_in[4];
    const float* cw0 = (const float*)d_in[5];
    const float* cb0 = (const float*)d_in[6];
    const float* cw1 = (const float*)d_in[7];
    const float* cb1 = (const float*)d_in[8];
    const float* pw  = (const float*)d_in[9];
    const float* pb  = (const float*)d_in[10];
    const int*   eidx = (const int*)d_in[11];

    const int N = in_sizes[0] / 128;
    const int E = in_sizes[11] / 2;
    const int B = (N + BNODES - 1) >> SHIFT;

    // workspace carve-out (~66.6 MB); X region serves h -> pairs -> agg
    char* w = (char*)d_ws;
    float* hwb     = (float*)w; w += (size_t)N * 16 * 4;
    float* dinv    = (float*)w; w += (size_t)N * 4;
    int*   cnt     = (int*)w;   w += (size_t)N * 4;
    int*   row_st  = (int*)w;   w += (size_t)N * 4;
    int*   csr     = (int*)w;   w += (size_t)E * 4;
    char*  X       = w;         w += (size_t)E * 4;
    int*   bcnt    = (int*)w;   w += BMAX * 4;
    int*   bbase   = (int*)w;   w += (BMAX + 1) * 4;
    int*   gcur    = (int*)w;   w += BMAX * 4;

    float* h     = (float*)X;   // live: mlp -> hw1
    int*   pairs = (int*)X;     // live: partition -> build_csr
    float* agg   = (float*)X;   // live: gather1 -> final

    float* out  = (float*)d_out;
    float* hout = out + N;

    const int nb_n = (N + 255) / 256;
    const int nb_g = (N * 16 + 255) / 256;
    const int nb_p = (E + 8191) / 8192;

    zero_kernel<<<1, BMAX, 0, stream>>>(bcnt);
    bucket_count<<<1024, 256, 0, stream>>>(eidx, bcnt, E, N, B);
    scan_kernel<<<1, BMAX, 0, stream>>>(bcnt, bbase, gcur, B);
    mlp_kernel<<<N / 64, 256, 0, stream>>>(x, W1, b1, W2, b2, h, N);
    hw_kernel<<<nb_n, 256, 0, stream>>>(h, cw0, nullptr, hwb, N, 0);   // h dead after this
    partition_kernel<<<nb_p, 256, 0, stream>>>(eidx, gcur, pairs, E, N, B);
    build_csr<<<B, 512, 0, stream>>>(pairs, bbase, row_st, cnt, dinv, csr, N);
    gather_kernel<<<nb_g, 256, 0, stream>>>(hwb, dinv, csr, row_st, cnt, agg, N); // pairs dead
    hw_kernel<<<nb_n, 256, 0, stream>>>(agg, cw1, cb0, hwb, N, 1);
    gather_kernel<<<nb_g, 256, 0, stream>>>(hwb, dinv, csr, row_st, cnt, agg, N);
    final_kernel<<<nb_n, 256, 0, stream>>>(agg, cb1, pw, pb, out, hout, N);
}

// Round 3
// 720.938 us; speedup vs baseline: 2.3611x; 1.5844x over previous
//
#include <hip/hip_runtime.h>

// NodeGNN: h = lrelu(lrelu(x@W1+b1)@W2+b2); 2x GCNConv(16->16) over E=6.4M edges
// + self loops with symmetric norm; out = sum(h@pw+pb, -1). Returns (out[N], h[N,16]).
//
// R3: MLP moved to bf16 MFMA (16x16x32). R2's fp32 MLP was 543us: 8-way LDS bank
// conflicts (1.9e8) + 64KB LDS capping occupancy at 2 blocks/CU. bf16 rounding in
// h_mlp is attenuated ~10x per conv by degree-normalized averaging -> negligible
// in validated outputs. CSR build stays as R2 (bucketed, L2-confined scatter).

#define NEG 0.01f
#define SHIFT 9                 // 512 nodes per bucket
#define BNODES (1 << SHIFT)
#define BMAX 512                // max buckets (N <= 262144)

typedef __attribute__((ext_vector_type(8))) short short8;
typedef __attribute__((ext_vector_type(4))) float floatx4;
typedef __attribute__((ext_vector_type(4))) unsigned short us4;

__device__ __forceinline__ float lrelu(float v) { return v >= 0.0f ? v : NEG * v; }

__device__ __forceinline__ unsigned short f2bf(float f) {
    unsigned int u = __float_as_uint(f);
    u += 0x7fffu + ((u >> 16) & 1u);          // round-to-nearest-even
    return (unsigned short)(u >> 16);
}

// ---------------------------------------------------------------------------
// K-prep: bf16-transposed weights. W1T[n][k] = bf16(W1[k][n]) (256x128),
// W2T[c][k] = bf16(W2[k][c]) (16x256). 128KB of reads, L2-resident, tiny.
// ---------------------------------------------------------------------------
__global__ void prep_kernel(const float* __restrict__ W1, const float* __restrict__ W2,
                            unsigned short* __restrict__ W1T, unsigned short* __restrict__ W2T)
{
    const int idx = blockIdx.x * 256 + threadIdx.x;
    const int stride = gridDim.x * 256;
    for (int i = idx; i < 256 * 128; i += stride) {
        int n = i >> 7, k = i & 127;
        W1T[i] = f2bf(W1[k * 256 + n]);
    }
    for (int i = idx; i < 16 * 256; i += stride) {
        int c = i >> 8, k = i & 255;
        W2T[i] = f2bf(W2[k * 16 + c]);
    }
}

// ---------------------------------------------------------------------------
// K1: MFMA MLP. Block = 256 threads (4 waves), 64 nodes/block.
// Layer 1: per wave 64 N-cols: 4m x 4n x 4k MFMAs, A from LDS bf16 x-tile,
//          B from global W1T (L2). h1 -> LDS bf16 [64][264] (padded, 2-way free).
// Layer 2: per wave 16 nodes: 8 MFMAs vs W2T. Epilogue writes h fp32 [N][16].
// LDS 50KB -> 3 blocks/CU; ~160 VGPR -> 3 waves/SIMD.
// ---------------------------------------------------------------------------
__global__ __launch_bounds__(256, 3) void mlp_mfma(
    const float* __restrict__ x, const unsigned short* __restrict__ W1T,
    const float* __restrict__ b1, const unsigned short* __restrict__ W2T,
    const float* __restrict__ b2, float* __restrict__ h, int N)
{
    __shared__ unsigned short xbf[64][136];   // 17.0 KB (pad 128->136: frag reads 2-way)
    __shared__ unsigned short h1s[64][264];   // 33.8 KB (pad 256->264)

    const int tid  = threadIdx.x;
    const int n0   = blockIdx.x * 64;
    const int lane = tid & 63;
    const int lr   = lane & 15;               // row-in-tile (A/C) / col-in-tile (B/C)
    const int quad = lane >> 4;
    const int wv   = tid >> 6;

    // stage 0: x tile fp32 -> bf16 LDS (coalesced float4 reads)
    {
        const float4* xg = (const float4*)(x + (size_t)n0 * 128);
#pragma unroll
        for (int i = 0; i < 8; ++i) {
            int f = tid + 256 * i;            // float4 index in 64x32
            float4 v = xg[f];
            int r = f >> 5, c = (f & 31) * 4;
            us4 p;
            p.x = f2bf(v.x); p.y = f2bf(v.y); p.z = f2bf(v.z); p.w = f2bf(v.w);
            *(us4*)&xbf[r][c] = p;
        }
    }
    __syncthreads();

    // layer 1: A-frags for all 4 m-tiles x 4 k-tiles (held in regs, 64 VGPRs)
    short8 af[4][4];
#pragma unroll
    for (int m = 0; m < 4; ++m)
#pragma unroll
        for (int kt = 0; kt < 4; ++kt)
            af[m][kt] = *(const short8*)&xbf[m * 16 + lr][kt * 32 + quad * 8];

    floatx4 acc[4][4];
#pragma unroll
    for (int n = 0; n < 4; ++n)
#pragma unroll
        for (int m = 0; m < 4; ++m)
            acc[n][m] = (floatx4){0.f, 0.f, 0.f, 0.f};

    const int nbase = wv * 64;
#pragma unroll
    for (int n = 0; n < 4; ++n) {
        const unsigned short* bp = &W1T[(size_t)(nbase + n * 16 + lr) * 128 + quad * 8];
        short8 bfr[4];
#pragma unroll
        for (int kt = 0; kt < 4; ++kt) bfr[kt] = *(const short8*)(bp + kt * 32);
#pragma unroll
        for (int kt = 0; kt < 4; ++kt)
#pragma unroll
            for (int m = 0; m < 4; ++m)
                acc[n][m] = __builtin_amdgcn_mfma_f32_16x16x32_bf16(
                    af[m][kt], bfr[kt], acc[n][m], 0, 0, 0);
    }

    // epilogue 1: +b1, lrelu, bf16 -> h1s (C layout: col=lr, row=quad*4+reg)
#pragma unroll
    for (int n = 0; n < 4; ++n) {
        float bc = b1[nbase + n * 16 + lr];
#pragma unroll
        for (int m = 0; m < 4; ++m)
#pragma unroll
            for (int reg = 0; reg < 4; ++reg) {
                float v = lrelu(acc[n][m][reg] + bc);
                h1s[m * 16 + quad * 4 + reg][nbase + n * 16 + lr] = f2bf(v);
            }
    }
    __syncthreads();

    // layer 2: wave wv owns nodes wv*16..+15; 8 k-tiles over 256
    floatx4 acc2 = (floatx4){0.f, 0.f, 0.f, 0.f};
#pragma unroll
    for (int kt = 0; kt < 8; ++kt) {
        short8 a2 = *(const short8*)&h1s[wv * 16 + lr][kt * 32 + quad * 8];
        short8 b2f = *(const short8*)&W2T[lr * 256 + kt * 32 + quad * 8];
        acc2 = __builtin_amdgcn_mfma_f32_16x16x32_bf16(a2, b2f, acc2, 0, 0, 0);
    }
    float bb = b2[lr];
#pragma unroll
    for (int reg = 0; reg < 4; ++reg) {
        int r = n0 + wv * 16 + quad * 4 + reg;
        h[(size_t)r * 16 + lr] = lrelu(acc2[reg] + bb);
    }
}

// ---------------------------------------------------------------------------
// K0: zero the global bucket counters
// ---------------------------------------------------------------------------
__global__ void zero_kernel(int* __restrict__ bcnt)
{
    bcnt[threadIdx.x] = 0;
}

// ---------------------------------------------------------------------------
// K2: per-bucket edge histogram (LDS-aggregated)
// ---------------------------------------------------------------------------
__global__ __launch_bounds__(256) void bucket_count(
    const int* __restrict__ eidx, int* __restrict__ bcnt, int E, int N, int B)
{
    __shared__ int hist[BMAX];
    const int t = threadIdx.x;
    for (int b = t; b < B; b += 256) hist[b] = 0;
    __syncthreads();

    const int stride = gridDim.x * 256;
    for (int e = blockIdx.x * 256 + t; e < E; e += stride) {
        int d = eidx[E + e];
        d = min(max(d, 0), N - 1);
        atomicAdd(&hist[d >> SHIFT], 1);
    }
    __syncthreads();
    for (int b = t; b < B; b += 256) {
        int c = hist[b];
        if (c) atomicAdd(&bcnt[b], c);
    }
}

// ---------------------------------------------------------------------------
// K3: single-block exclusive scan over bucket counts
// ---------------------------------------------------------------------------
__global__ __launch_bounds__(512) void scan_kernel(
    const int* __restrict__ bcnt, int* __restrict__ bbase, int* __restrict__ gcur, int B)
{
    __shared__ int s[BMAX];
    const int t = threadIdx.x;        // 512 threads
    int c = (t < B) ? bcnt[t] : 0;
    s[t] = c;
    __syncthreads();
#pragma unroll
    for (int off = 1; off < BMAX; off <<= 1) {
        int v = s[t];
        int u = (t >= off) ? s[t - off] : 0;
        __syncthreads();
        s[t] = v + u;
        __syncthreads();
    }
    if (t < B) {
        int excl = s[t] - c;
        bbase[t] = excl;
        gcur[t]  = excl;
    }
    if (t == 0) bbase[B] = s[BMAX - 1];
}

// ---------------------------------------------------------------------------
// K4: partition edges into bucket runs (packed src<<9 | dst&511)
// ---------------------------------------------------------------------------
__global__ __launch_bounds__(256) void partition_kernel(
    const int* __restrict__ eidx, int* __restrict__ gcur, int* __restrict__ pairs,
    int E, int N, int B)
{
    __shared__ int hist[BMAX];
    __shared__ int basec[BMAX];
    const int t  = threadIdx.x;
    const int e0 = blockIdx.x * 8192;
    const int elim = min(8192, E - e0);

    for (int b = t; b < B; b += 256) hist[b] = 0;
    __syncthreads();

    for (int i = t; i < elim; i += 256) {
        int d = eidx[E + e0 + i];
        d = min(max(d, 0), N - 1);
        atomicAdd(&hist[d >> SHIFT], 1);
    }
    __syncthreads();
    for (int b = t; b < B; b += 256) {
        int c = hist[b];
        basec[b] = c ? atomicAdd(&gcur[b], c) : 0;
    }
    __syncthreads();
    for (int i = t; i < elim; i += 256) {
        int s = eidx[e0 + i];
        int d = eidx[E + e0 + i];
        s = min(max(s, 0), N - 1);
        d = min(max(d, 0), N - 1);
        int b = d >> SHIFT;
        int p = atomicAdd(&basec[b], 1);
        pairs[p] = (s << SHIFT) | (d & (BNODES - 1));
    }
}

// ---------------------------------------------------------------------------
// K5: per-bucket counting sort -> csr, plus row_start/cnt/dinv
// ---------------------------------------------------------------------------
__global__ __launch_bounds__(512) void build_csr(
    const int* __restrict__ pairs, const int* __restrict__ bbase,
    int* __restrict__ row_start, int* __restrict__ cnt_out, float* __restrict__ dinv,
    int* __restrict__ csr, int N)
{
    __shared__ int cnt[BNODES];
    __shared__ int off[BNODES];
    const int b = blockIdx.x, t = threadIdx.x;   // 512 threads
    const int node0 = b << SHIFT;
    const int lo = bbase[b], hi = bbase[b + 1];

    cnt[t] = 0;
    __syncthreads();
    for (int e = lo + t; e < hi; e += 512)
        atomicAdd(&cnt[pairs[e] & (BNODES - 1)], 1);
    __syncthreads();

    int c = cnt[t];
    off[t] = c;
    __syncthreads();
#pragma unroll
    for (int o = 1; o < BNODES; o <<= 1) {
        int v = off[t];
        int u = (t >= o) ? off[t - o] : 0;
        __syncthreads();
        off[t] = v + u;
        __syncthreads();
    }
    const int excl = off[t] - c;
    const int node = node0 + t;
    if (node < N) {
        row_start[node] = lo + excl;
        cnt_out[node]   = c;
        dinv[node]      = rsqrtf((float)(c + 1));
    }
    cnt[t] = lo + excl;              // reuse as cursor
    __syncthreads();
    for (int e = lo + t; e < hi; e += 512) {
        int v = pairs[e];
        int p = atomicAdd(&cnt[v & (BNODES - 1)], 1);
        csr[p] = v >> SHIFT;
    }
}

// ---------------------------------------------------------------------------
// K6: hw = (optionally lrelu(in + bias_prev)) @ W[16x16]. Thread per node.
// ---------------------------------------------------------------------------
__global__ void hw_kernel(const float* __restrict__ in, const float* __restrict__ W,
                          const float* __restrict__ bias, float* __restrict__ out,
                          int N, int apply)
{
    int i = blockIdx.x * 256 + threadIdx.x;
    if (i >= N) return;
    const float4* ir = (const float4*)(in + (size_t)i * 16);
    float4 r0 = ir[0], r1 = ir[1], r2 = ir[2], r3 = ir[3];
    float v[16] = {r0.x, r0.y, r0.z, r0.w, r1.x, r1.y, r1.z, r1.w,
                   r2.x, r2.y, r2.z, r2.w, r3.x, r3.y, r3.z, r3.w};
    if (apply) {
#pragma unroll
        for (int c = 0; c < 16; ++c) v[c] = lrelu(v[c] + bias[c]);
    }
    float o[16];
#pragma unroll
    for (int c = 0; c < 16; ++c) o[c] = 0.0f;
#pragma unroll
    for (int k = 0; k < 16; ++k) {
        float vk = v[k];
#pragma unroll
        for (int c = 0; c < 16; ++c) o[c] += vk * W[k * 16 + c];
    }
    float4* orow = (float4*)(out + (size_t)i * 16);
    orow[0] = make_float4(o[0],  o[1],  o[2],  o[3]);
    orow[1] = make_float4(o[4],  o[5],  o[6],  o[7]);
    orow[2] = make_float4(o[8],  o[9],  o[10], o[11]);
    orow[3] = make_float4(o[12], o[13], o[14], o[15]);
}

// ---------------------------------------------------------------------------
// K7: gather conv. 16 lanes per node, lane c owns feature c.
// ---------------------------------------------------------------------------
__global__ __launch_bounds__(256) void gather_kernel(
    const float* __restrict__ hw, const float* __restrict__ dinv,
    const int* __restrict__ csr, const int* __restrict__ row_start,
    const int* __restrict__ cnt, float* __restrict__ agg, int N)
{
    int t    = blockIdx.x * 256 + threadIdx.x;
    int node = t >> 4;
    int c    = t & 15;
    if (node >= N) return;

    int   s0 = row_start[node];
    int   n  = cnt[node];
    float di = dinv[node];
    float acc = hw[node * 16 + c] * di;

    int j = 0;
    for (; j + 4 <= n; j += 4) {
        int sa = csr[s0 + j + 0]; int sb = csr[s0 + j + 1];
        int sc = csr[s0 + j + 2]; int sd = csr[s0 + j + 3];
        float ga = hw[sa * 16 + c], gb = hw[sb * 16 + c];
        float gc = hw[sc * 16 + c], gd = hw[sd * 16 + c];
        float da = dinv[sa], db = dinv[sb], dc = dinv[sc], dd = dinv[sd];
        acc += ga * da; acc += gb * db; acc += gc * dc; acc += gd * dd;
    }
    for (; j < n; ++j) {
        int s = csr[s0 + j];
        acc += hw[s * 16 + c] * dinv[s];
    }
    agg[node * 16 + c] = acc * di;
}

// ---------------------------------------------------------------------------
// K8: final head. h = lrelu(agg + cb1); out = h . (pw[:,0]+pw[:,1]) + pb0+pb1
// ---------------------------------------------------------------------------
__global__ void final_kernel(const float* __restrict__ agg, const float* __restrict__ cb1,
                             const float* __restrict__ pw, const float* __restrict__ pb,
                             float* __restrict__ out, float* __restrict__ hout, int N)
{
    int i = blockIdx.x * 256 + threadIdx.x;
    if (i >= N) return;
    const float4* ar = (const float4*)(agg + (size_t)i * 16);
    float4 r0 = ar[0], r1 = ar[1], r2 = ar[2], r3 = ar[3];
    float v[16] = {r0.x, r0.y, r0.z, r0.w, r1.x, r1.y, r1.z, r1.w,
                   r2.x, r2.y, r2.z, r2.w, r3.x, r3.y, r3.z, r3.w};
    float s = pb[0] + pb[1];
#pragma unroll
    for (int c = 0; c < 16; ++c) {
        v[c] = lrelu(v[c] + cb1[c]);
        s += v[c] * (pw[c * 2] + pw[c * 2 + 1]);
    }
    out[i] = s;
    float4* hr = (float4*)(hout + (size_t)i * 16);
    hr[0] = make_float4(v[0],  v[1],  v[2],  v[3]);
    hr[1] = make_float4(v[4],  v[5],  v[6],  v[7]);
    hr[2] = make_float4(v[8],  v[9],  v[10], v[11]);
    hr[3] = make_float4(v[12], v[13], v[14], v[15]);
}

// ---------------------------------------------------------------------------
extern "C" void kernel_launch(void* const* d_in, const int* in_sizes, int n_in,
                              void* d_out, int out_size, void* d_ws, size_t ws_size,
                              hipStream_t stream)
{
    const float* x   = (const float*)d_in[0];
    const float* W1  = (const float*)d_in[1];
    const float* b1  = (const float*)d_in[2];
    const float* W2  = (const float*)d_in[3];
    const float* b2  = (const float*)d_in[4];
    const float* cw0 = (const float*)d_in[5];
    const float* cb0 = (const float*)d_in[6];
    const float* cw1 = (const float*)d_in[7];
    const float* cb1 = (const float*)d_in[8];
    const float* pw  = (const float*)d_in[9];
    const float* pb  = (const float*)d_in[10];
    const int*   eidx = (const int*)d_in[11];

    const int N = in_sizes[0] / 128;
    const int E = in_sizes[11] / 2;
    const int B = (N + BNODES - 1) >> SHIFT;

    // workspace carve-out (~66.7 MB); X region serves h -> pairs -> agg
    char* w = (char*)d_ws;
    float* hwb     = (float*)w; w += (size_t)N * 16 * 4;
    float* dinv    = (float*)w; w += (size_t)N * 4;
    int*   cnt     = (int*)w;   w += (size_t)N * 4;
    int*   row_st  = (int*)w;   w += (size_t)N * 4;
    int*   csr     = (int*)w;   w += (size_t)E * 4;
    char*  X       = w;         w += (size_t)E * 4;
    int*   bcnt    = (int*)w;   w += BMAX * 4;
    int*   bbase   = (int*)w;   w += (BMAX + 4) * 4;   // +4 keeps 16B alignment below
    int*   gcur    = (int*)w;   w += BMAX * 4;
    unsigned short* W1T = (unsigned short*)w; w += 256 * 128 * 2;  // 16B-aligned
    unsigned short* W2T = (unsigned short*)w; w += 16 * 256 * 2;

    float* h     = (float*)X;   // live: mlp -> hw1
    int*   pairs = (int*)X;     // live: partition -> build_csr
    float* agg   = (float*)X;   // live: gather1 -> final

    float* out  = (float*)d_out;
    float* hout = out + N;

    const int nb_n = (N + 255) / 256;
    const int nb_g = (N * 16 + 255) / 256;
    const int nb_p = (E + 8191) / 8192;

    zero_kernel<<<1, BMAX, 0, stream>>>(bcnt);
    bucket_count<<<1024, 256, 0, stream>>>(eidx, bcnt, E, N, B);
    scan_kernel<<<1, BMAX, 0, stream>>>(bcnt, bbase, gcur, B);
    prep_kernel<<<32, 256, 0, stream>>>(W1, W2, W1T, W2T);
    mlp_mfma<<<N / 64, 256, 0, stream>>>(x, W1T, b1, W2T, b2, h, N);
    hw_kernel<<<nb_n, 256, 0, stream>>>(h, cw0, nullptr, hwb, N, 0);   // h dead after this
    partition_kernel<<<nb_p, 256, 0, stream>>>(eidx, gcur, pairs, E, N, B);
    build_csr<<<B, 512, 0, stream>>>(pairs, bbase, row_st, cnt, dinv, csr, N);
    gather_kernel<<<nb_g, 256, 0, stream>>>(hwb, dinv, csr, row_st, cnt, agg, N); // pairs dead
    hw_kernel<<<nb_n, 256, 0, stream>>>(agg, cw1, cb0, hwb, N, 1);
    gather_kernel<<<nb_g, 256, 0, stream>>>(hwb, dinv, csr, row_st, cnt, agg, N);
    final_kernel<<<nb_n, 256, 0, stream>>>(agg, cb1, pw, pb, out, hout, N);
}

// Round 4
// 628.541 us; speedup vs baseline: 2.7082x; 1.1470x over previous
//
#include <hip/hip_runtime.h>

// NodeGNN: h = lrelu(lrelu(x@W1+b1)@W2+b2); 2x GCNConv(16->16) over E=6.4M edges
// + self loops with symmetric norm; out = sum(h@pw+pb, -1). Returns (out[N], h[N,16]).
//
// R4: partition_kernel rewritten — R3 version did 6.4M scattered 4B global writes
// (WRITE_SIZE 163MB vs 25.6MB compulsory, 146us). Now each block counting-sorts its
// 8192-edge chunk in LDS (38KB) and flushes bucket runs with consecutive-address
// stores (full-line coalescing); bucket-of-slot via 9-step LDS binary search.

#define NEG 0.01f
#define SHIFT 9                 // 512 nodes per bucket
#define BNODES (1 << SHIFT)
#define BMAX 512                // max buckets (N <= 262144)
#define PCHUNK 8192             // edges per partition block

typedef __attribute__((ext_vector_type(8))) short short8;
typedef __attribute__((ext_vector_type(4))) float floatx4;
typedef __attribute__((ext_vector_type(4))) unsigned short us4;

__device__ __forceinline__ float lrelu(float v) { return v >= 0.0f ? v : NEG * v; }

__device__ __forceinline__ unsigned short f2bf(float f) {
    unsigned int u = __float_as_uint(f);
    u += 0x7fffu + ((u >> 16) & 1u);          // round-to-nearest-even
    return (unsigned short)(u >> 16);
}

// ---------------------------------------------------------------------------
// K-prep: bf16-transposed weights. W1T[n][k] = bf16(W1[k][n]) (256x128),
// W2T[c][k] = bf16(W2[k][c]) (16x256).
// ---------------------------------------------------------------------------
__global__ void prep_kernel(const float* __restrict__ W1, const float* __restrict__ W2,
                            unsigned short* __restrict__ W1T, unsigned short* __restrict__ W2T)
{
    const int idx = blockIdx.x * 256 + threadIdx.x;
    const int stride = gridDim.x * 256;
    for (int i = idx; i < 256 * 128; i += stride) {
        int n = i >> 7, k = i & 127;
        W1T[i] = f2bf(W1[k * 256 + n]);
    }
    for (int i = idx; i < 16 * 256; i += stride) {
        int c = i >> 8, k = i & 255;
        W2T[i] = f2bf(W2[k * 16 + c]);
    }
}

// ---------------------------------------------------------------------------
// K1: MFMA MLP. Block = 256 threads (4 waves), 64 nodes/block. (unchanged R3)
// ---------------------------------------------------------------------------
__global__ __launch_bounds__(256, 3) void mlp_mfma(
    const float* __restrict__ x, const unsigned short* __restrict__ W1T,
    const float* __restrict__ b1, const unsigned short* __restrict__ W2T,
    const float* __restrict__ b2, float* __restrict__ h, int N)
{
    __shared__ unsigned short xbf[64][136];   // 17.0 KB
    __shared__ unsigned short h1s[64][264];   // 33.8 KB

    const int tid  = threadIdx.x;
    const int n0   = blockIdx.x * 64;
    const int lane = tid & 63;
    const int lr   = lane & 15;
    const int quad = lane >> 4;
    const int wv   = tid >> 6;

    {
        const float4* xg = (const float4*)(x + (size_t)n0 * 128);
#pragma unroll
        for (int i = 0; i < 8; ++i) {
            int f = tid + 256 * i;
            float4 v = xg[f];
            int r = f >> 5, c = (f & 31) * 4;
            us4 p;
            p.x = f2bf(v.x); p.y = f2bf(v.y); p.z = f2bf(v.z); p.w = f2bf(v.w);
            *(us4*)&xbf[r][c] = p;
        }
    }
    __syncthreads();

    short8 af[4][4];
#pragma unroll
    for (int m = 0; m < 4; ++m)
#pragma unroll
        for (int kt = 0; kt < 4; ++kt)
            af[m][kt] = *(const short8*)&xbf[m * 16 + lr][kt * 32 + quad * 8];

    floatx4 acc[4][4];
#pragma unroll
    for (int n = 0; n < 4; ++n)
#pragma unroll
        for (int m = 0; m < 4; ++m)
            acc[n][m] = (floatx4){0.f, 0.f, 0.f, 0.f};

    const int nbase = wv * 64;
#pragma unroll
    for (int n = 0; n < 4; ++n) {
        const unsigned short* bp = &W1T[(size_t)(nbase + n * 16 + lr) * 128 + quad * 8];
        short8 bfr[4];
#pragma unroll
        for (int kt = 0; kt < 4; ++kt) bfr[kt] = *(const short8*)(bp + kt * 32);
#pragma unroll
        for (int kt = 0; kt < 4; ++kt)
#pragma unroll
            for (int m = 0; m < 4; ++m)
                acc[n][m] = __builtin_amdgcn_mfma_f32_16x16x32_bf16(
                    af[m][kt], bfr[kt], acc[n][m], 0, 0, 0);
    }

#pragma unroll
    for (int n = 0; n < 4; ++n) {
        float bc = b1[nbase + n * 16 + lr];
#pragma unroll
        for (int m = 0; m < 4; ++m)
#pragma unroll
            for (int reg = 0; reg < 4; ++reg) {
                float v = lrelu(acc[n][m][reg] + bc);
                h1s[m * 16 + quad * 4 + reg][nbase + n * 16 + lr] = f2bf(v);
            }
    }
    __syncthreads();

    floatx4 acc2 = (floatx4){0.f, 0.f, 0.f, 0.f};
#pragma unroll
    for (int kt = 0; kt < 8; ++kt) {
        short8 a2 = *(const short8*)&h1s[wv * 16 + lr][kt * 32 + quad * 8];
        short8 b2f = *(const short8*)&W2T[lr * 256 + kt * 32 + quad * 8];
        acc2 = __builtin_amdgcn_mfma_f32_16x16x32_bf16(a2, b2f, acc2, 0, 0, 0);
    }
    float bb = b2[lr];
#pragma unroll
    for (int reg = 0; reg < 4; ++reg) {
        int r = n0 + wv * 16 + quad * 4 + reg;
        h[(size_t)r * 16 + lr] = lrelu(acc2[reg] + bb);
    }
}

// ---------------------------------------------------------------------------
// K0: zero the global bucket counters
// ---------------------------------------------------------------------------
__global__ void zero_kernel(int* __restrict__ bcnt)
{
    bcnt[threadIdx.x] = 0;
}

// ---------------------------------------------------------------------------
// K2: per-bucket edge histogram (LDS-aggregated)
// ---------------------------------------------------------------------------
__global__ __launch_bounds__(256) void bucket_count(
    const int* __restrict__ eidx, int* __restrict__ bcnt, int E, int N, int B)
{
    __shared__ int hist[BMAX];
    const int t = threadIdx.x;
    for (int b = t; b < B; b += 256) hist[b] = 0;
    __syncthreads();

    const int stride = gridDim.x * 256;
    for (int e = blockIdx.x * 256 + t; e < E; e += stride) {
        int d = eidx[E + e];
        d = min(max(d, 0), N - 1);
        atomicAdd(&hist[d >> SHIFT], 1);
    }
    __syncthreads();
    for (int b = t; b < B; b += 256) {
        int c = hist[b];
        if (c) atomicAdd(&bcnt[b], c);
    }
}

// ---------------------------------------------------------------------------
// K3: single-block exclusive scan over bucket counts
// ---------------------------------------------------------------------------
__global__ __launch_bounds__(512) void scan_kernel(
    const int* __restrict__ bcnt, int* __restrict__ bbase, int* __restrict__ gcur, int B)
{
    __shared__ int s[BMAX];
    const int t = threadIdx.x;        // 512 threads
    int c = (t < B) ? bcnt[t] : 0;
    s[t] = c;
    __syncthreads();
#pragma unroll
    for (int off = 1; off < BMAX; off <<= 1) {
        int v = s[t];
        int u = (t >= off) ? s[t - off] : 0;
        __syncthreads();
        s[t] = v + u;
        __syncthreads();
    }
    if (t < B) {
        int excl = s[t] - c;
        bbase[t] = excl;
        gcur[t]  = excl;
    }
    if (t == 0) bbase[B] = s[BMAX - 1];
}

// ---------------------------------------------------------------------------
// K4: partition via block-level LDS counting sort + coalesced run flush.
// 512 threads, 8192 edges/block. LDS ~38KB.
// ---------------------------------------------------------------------------
__global__ __launch_bounds__(512) void partition_kernel(
    const int* __restrict__ eidx, int* __restrict__ gcur, int* __restrict__ pairs,
    int E, int N, int B)
{
    __shared__ int hist[BMAX];        // count -> cursor
    __shared__ int offx[BMAX + 1];    // exclusive local offsets (kept intact)
    __shared__ int basec[BMAX];       // global run base for this block
    __shared__ int sorted[PCHUNK];    // 32KB; doubles as scan scratch
    const int t  = threadIdx.x;
    const int e0 = blockIdx.x * PCHUNK;
    const int elim = min(PCHUNK, E - e0);

    hist[t] = 0;
    __syncthreads();
    for (int i = t; i < elim; i += 512) {
        int d = eidx[E + e0 + i];
        d = min(max(d, 0), N - 1);
        atomicAdd(&hist[d >> SHIFT], 1);
    }
    __syncthreads();

    // exclusive scan of hist into offx (Hillis-Steele in sorted[] scratch)
    int c = hist[t];
    sorted[t] = c;
    __syncthreads();
#pragma unroll
    for (int o = 1; o < BMAX; o <<= 1) {
        int v = sorted[t];
        int u = (t >= o) ? sorted[t - o] : 0;
        __syncthreads();
        sorted[t] = v + u;
        __syncthreads();
    }
    const int excl = sorted[t] - c;
    offx[t] = excl;
    if (t == 0) offx[BMAX] = elim;
    basec[t] = (t < B && c) ? atomicAdd(&gcur[t], c) : 0;
    hist[t] = excl;                   // becomes local cursor
    __syncthreads();

    // scatter into LDS (all conflicts confined to LDS)
    for (int i = t; i < elim; i += 512) {
        int s = eidx[e0 + i];
        int d = eidx[E + e0 + i];
        s = min(max(s, 0), N - 1);
        d = min(max(d, 0), N - 1);
        int b = d >> SHIFT;
        int p = atomicAdd(&hist[b], 1);
        sorted[p] = (s << SHIFT) | (d & (BNODES - 1));
    }
    __syncthreads();

    // coalesced flush: consecutive lanes -> consecutive slots -> consecutive
    // global addresses within each run. Bucket via binary search over offx
    // (largest b with offx[b] <= slot; ties resolve to the non-empty bucket).
    for (int slot = t; slot < elim; slot += 512) {
        int v = sorted[slot];
        int l = 0, r = BMAX - 1;
#pragma unroll
        for (int it = 0; it < 9; ++it) {
            int m = (l + r + 1) >> 1;
            if (offx[m] <= slot) l = m; else r = m - 1;
        }
        pairs[basec[l] + (slot - offx[l])] = v;
    }
}

// ---------------------------------------------------------------------------
// K5: per-bucket counting sort -> csr, plus row_start/cnt/dinv
// ---------------------------------------------------------------------------
__global__ __launch_bounds__(512) void build_csr(
    const int* __restrict__ pairs, const int* __restrict__ bbase,
    int* __restrict__ row_start, int* __restrict__ cnt_out, float* __restrict__ dinv,
    int* __restrict__ csr, int N)
{
    __shared__ int cnt[BNODES];
    __shared__ int off[BNODES];
    const int b = blockIdx.x, t = threadIdx.x;   // 512 threads
    const int node0 = b << SHIFT;
    const int lo = bbase[b], hi = bbase[b + 1];

    cnt[t] = 0;
    __syncthreads();
    for (int e = lo + t; e < hi; e += 512)
        atomicAdd(&cnt[pairs[e] & (BNODES - 1)], 1);
    __syncthreads();

    int c = cnt[t];
    off[t] = c;
    __syncthreads();
#pragma unroll
    for (int o = 1; o < BNODES; o <<= 1) {
        int v = off[t];
        int u = (t >= o) ? off[t - o] : 0;
        __syncthreads();
        off[t] = v + u;
        __syncthreads();
    }
    const int excl = off[t] - c;
    const int node = node0 + t;
    if (node < N) {
        row_start[node] = lo + excl;
        cnt_out[node]   = c;
        dinv[node]      = rsqrtf((float)(c + 1));
    }
    cnt[t] = lo + excl;              // reuse as cursor
    __syncthreads();
    for (int e = lo + t; e < hi; e += 512) {
        int v = pairs[e];
        int p = atomicAdd(&cnt[v & (BNODES - 1)], 1);
        csr[p] = v >> SHIFT;
    }
}

// ---------------------------------------------------------------------------
// K6: hw = (optionally lrelu(in + bias_prev)) @ W[16x16]. Thread per node.
// ---------------------------------------------------------------------------
__global__ void hw_kernel(const float* __restrict__ in, const float* __restrict__ W,
                          const float* __restrict__ bias, float* __restrict__ out,
                          int N, int apply)
{
    int i = blockIdx.x * 256 + threadIdx.x;
    if (i >= N) return;
    const float4* ir = (const float4*)(in + (size_t)i * 16);
    float4 r0 = ir[0], r1 = ir[1], r2 = ir[2], r3 = ir[3];
    float v[16] = {r0.x, r0.y, r0.z, r0.w, r1.x, r1.y, r1.z, r1.w,
                   r2.x, r2.y, r2.z, r2.w, r3.x, r3.y, r3.z, r3.w};
    if (apply) {
#pragma unroll
        for (int c = 0; c < 16; ++c) v[c] = lrelu(v[c] + bias[c]);
    }
    float o[16];
#pragma unroll
    for (int c = 0; c < 16; ++c) o[c] = 0.0f;
#pragma unroll
    for (int k = 0; k < 16; ++k) {
        float vk = v[k];
#pragma unroll
        for (int c = 0; c < 16; ++c) o[c] += vk * W[k * 16 + c];
    }
    float4* orow = (float4*)(out + (size_t)i * 16);
    orow[0] = make_float4(o[0],  o[1],  o[2],  o[3]);
    orow[1] = make_float4(o[4],  o[5],  o[6],  o[7]);
    orow[2] = make_float4(o[8],  o[9],  o[10], o[11]);
    orow[3] = make_float4(o[12], o[13], o[14], o[15]);
}

// ---------------------------------------------------------------------------
// K7: gather conv. 16 lanes per node, lane c owns feature c.
// ---------------------------------------------------------------------------
__global__ __launch_bounds__(256) void gather_kernel(
    const float* __restrict__ hw, const float* __restrict__ dinv,
    const int* __restrict__ csr, const int* __restrict__ row_start,
    const int* __restrict__ cnt, float* __restrict__ agg, int N)
{
    int t    = blockIdx.x * 256 + threadIdx.x;
    int node = t >> 4;
    int c    = t & 15;
    if (node >= N) return;

    int   s0 = row_start[node];
    int   n  = cnt[node];
    float di = dinv[node];
    float acc = hw[node * 16 + c] * di;

    int j = 0;
    for (; j + 4 <= n; j += 4) {
        int sa = csr[s0 + j + 0]; int sb = csr[s0 + j + 1];
        int sc = csr[s0 + j + 2]; int sd = csr[s0 + j + 3];
        float ga = hw[sa * 16 + c], gb = hw[sb * 16 + c];
        float gc = hw[sc * 16 + c], gd = hw[sd * 16 + c];
        float da = dinv[sa], db = dinv[sb], dc = dinv[sc], dd = dinv[sd];
        acc += ga * da; acc += gb * db; acc += gc * dc; acc += gd * dd;
    }
    for (; j < n; ++j) {
        int s = csr[s0 + j];
        acc += hw[s * 16 + c] * dinv[s];
    }
    agg[node * 16 + c] = acc * di;
}

// ---------------------------------------------------------------------------
// K8: final head. h = lrelu(agg + cb1); out = h . (pw[:,0]+pw[:,1]) + pb0+pb1
// ---------------------------------------------------------------------------
__global__ void final_kernel(const float* __restrict__ agg, const float* __restrict__ cb1,
                             const float* __restrict__ pw, const float* __restrict__ pb,
                             float* __restrict__ out, float* __restrict__ hout, int N)
{
    int i = blockIdx.x * 256 + threadIdx.x;
    if (i >= N) return;
    const float4* ar = (const float4*)(agg + (size_t)i * 16);
    float4 r0 = ar[0], r1 = ar[1], r2 = ar[2], r3 = ar[3];
    float v[16] = {r0.x, r0.y, r0.z, r0.w, r1.x, r1.y, r1.z, r1.w,
                   r2.x, r2.y, r2.z, r2.w, r3.x, r3.y, r3.z, r3.w};
    float s = pb[0] + pb[1];
#pragma unroll
    for (int c = 0; c < 16; ++c) {
        v[c] = lrelu(v[c] + cb1[c]);
        s += v[c] * (pw[c * 2] + pw[c * 2 + 1]);
    }
    out[i] = s;
    float4* hr = (float4*)(hout + (size_t)i * 16);
    hr[0] = make_float4(v[0],  v[1],  v[2],  v[3]);
    hr[1] = make_float4(v[4],  v[5],  v[6],  v[7]);
    hr[2] = make_float4(v[8],  v[9],  v[10], v[11]);
    hr[3] = make_float4(v[12], v[13], v[14], v[15]);
}

// ---------------------------------------------------------------------------
extern "C" void kernel_launch(void* const* d_in, const int* in_sizes, int n_in,
                              void* d_out, int out_size, void* d_ws, size_t ws_size,
                              hipStream_t stream)
{
    const float* x   = (const float*)d_in[0];
    const float* W1  = (const float*)d_in[1];
    const float* b1  = (const float*)d_in[2];
    const float* W2  = (const float*)d_in[3];
    const float* b2  = (const float*)d_in[4];
    const float* cw0 = (const float*)d_in[5];
    const float* cb0 = (const float*)d_in[6];
    const float* cw1 = (const float*)d_in[7];
    const float* cb1 = (const float*)d_in[8];
    const float* pw  = (const float*)d_in[9];
    const float* pb  = (const float*)d_in[10];
    const int*   eidx = (const int*)d_in[11];

    const int N = in_sizes[0] / 128;
    const int E = in_sizes[11] / 2;
    const int B = (N + BNODES - 1) >> SHIFT;

    // workspace carve-out (~66.7 MB); X region serves h -> pairs -> agg
    char* w = (char*)d_ws;
    float* hwb     = (float*)w; w += (size_t)N * 16 * 4;
    float* dinv    = (float*)w; w += (size_t)N * 4;
    int*   cnt     = (int*)w;   w += (size_t)N * 4;
    int*   row_st  = (int*)w;   w += (size_t)N * 4;
    int*   csr     = (int*)w;   w += (size_t)E * 4;
    char*  X       = w;         w += (size_t)E * 4;
    int*   bcnt    = (int*)w;   w += BMAX * 4;
    int*   bbase   = (int*)w;   w += (BMAX + 4) * 4;   // +4 keeps 16B alignment below
    int*   gcur    = (int*)w;   w += BMAX * 4;
    unsigned short* W1T = (unsigned short*)w; w += 256 * 128 * 2;  // 16B-aligned
    unsigned short* W2T = (unsigned short*)w; w += 16 * 256 * 2;

    float* h     = (float*)X;   // live: mlp -> hw1
    int*   pairs = (int*)X;     // live: partition -> build_csr
    float* agg   = (float*)X;   // live: gather1 -> final

    float* out  = (float*)d_out;
    float* hout = out + N;

    const int nb_n = (N + 255) / 256;
    const int nb_g = (N * 16 + 255) / 256;
    const int nb_p = (E + PCHUNK - 1) / PCHUNK;

    zero_kernel<<<1, BMAX, 0, stream>>>(bcnt);
    bucket_count<<<1024, 256, 0, stream>>>(eidx, bcnt, E, N, B);
    scan_kernel<<<1, BMAX, 0, stream>>>(bcnt, bbase, gcur, B);
    prep_kernel<<<32, 256, 0, stream>>>(W1, W2, W1T, W2T);
    mlp_mfma<<<N / 64, 256, 0, stream>>>(x, W1T, b1, W2T, b2, h, N);
    hw_kernel<<<nb_n, 256, 0, stream>>>(h, cw0, nullptr, hwb, N, 0);   // h dead after this
    partition_kernel<<<nb_p, 512, 0, stream>>>(eidx, gcur, pairs, E, N, B);
    build_csr<<<B, 512, 0, stream>>>(pairs, bbase, row_st, cnt, dinv, csr, N);
    gather_kernel<<<nb_g, 256, 0, stream>>>(hwb, dinv, csr, row_st, cnt, agg, N); // pairs dead
    hw_kernel<<<nb_n, 256, 0, stream>>>(agg, cw1, cb0, hwb, N, 1);
    gather_kernel<<<nb_g, 256, 0, stream>>>(hwb, dinv, csr, row_st, cnt, agg, N);
    final_kernel<<<nb_n, 256, 0, stream>>>(agg, cb1, pw, pb, out, hout, N);
}

// Round 5
// 586.180 us; speedup vs baseline: 2.9039x; 1.0723x over previous
//
#include <hip/hip_runtime.h>

// NodeGNN: h = lrelu(lrelu(x@W1+b1)@W2+b2); 2x GCNConv(16->16) over E=6.4M edges
// + self loops with symmetric norm; out = sum(h@pw+pb, -1). Returns (out[N], h[N,16]).
//
// R5: gather traffic halved — hw rows stored as bf16 (32B/row instead of 64B).
// R4 gathers were BW-bound: FETCH 349MB @ 3.5TB/s = 106us each, traffic = E x
// row_bytes. 8 lanes/node, uint loads (2 bf16 features), shift-unpack. dinv[src]
// gathered separately (800KB, L2-resident). Quantization attenuated by the
// degree-normalized average -> ~6e-4 on validated h.

#define NEG 0.01f
#define SHIFT 9                 // 512 nodes per bucket
#define BNODES (1 << SHIFT)
#define BMAX 512                // max buckets (N <= 262144)
#define PCHUNK 8192             // edges per partition block

typedef __attribute__((ext_vector_type(8))) short short8;
typedef __attribute__((ext_vector_type(4))) float floatx4;
typedef __attribute__((ext_vector_type(4))) unsigned short us4;
typedef __attribute__((ext_vector_type(8))) unsigned short us8;

__device__ __forceinline__ float lrelu(float v) { return v >= 0.0f ? v : NEG * v; }

__device__ __forceinline__ unsigned short f2bf(float f) {
    unsigned int u = __float_as_uint(f);
    u += 0x7fffu + ((u >> 16) & 1u);          // round-to-nearest-even
    return (unsigned short)(u >> 16);
}
__device__ __forceinline__ float bflo(unsigned int u) { return __uint_as_float(u << 16); }
__device__ __forceinline__ float bfhi(unsigned int u) { return __uint_as_float(u & 0xffff0000u); }

// ---------------------------------------------------------------------------
// K-prep: bf16-transposed weights. W1T[n][k] = bf16(W1[k][n]) (256x128),
// W2T[c][k] = bf16(W2[k][c]) (16x256).
// ---------------------------------------------------------------------------
__global__ void prep_kernel(const float* __restrict__ W1, const float* __restrict__ W2,
                            unsigned short* __restrict__ W1T, unsigned short* __restrict__ W2T)
{
    const int idx = blockIdx.x * 256 + threadIdx.x;
    const int stride = gridDim.x * 256;
    for (int i = idx; i < 256 * 128; i += stride) {
        int n = i >> 7, k = i & 127;
        W1T[i] = f2bf(W1[k * 256 + n]);
    }
    for (int i = idx; i < 16 * 256; i += stride) {
        int c = i >> 8, k = i & 255;
        W2T[i] = f2bf(W2[k * 16 + c]);
    }
}

// ---------------------------------------------------------------------------
// K1: MFMA MLP. Block = 256 threads (4 waves), 64 nodes/block. (unchanged R3)
// ---------------------------------------------------------------------------
__global__ __launch_bounds__(256, 3) void mlp_mfma(
    const float* __restrict__ x, const unsigned short* __restrict__ W1T,
    const float* __restrict__ b1, const unsigned short* __restrict__ W2T,
    const float* __restrict__ b2, float* __restrict__ h, int N)
{
    __shared__ unsigned short xbf[64][136];   // 17.0 KB
    __shared__ unsigned short h1s[64][264];   // 33.8 KB

    const int tid  = threadIdx.x;
    const int n0   = blockIdx.x * 64;
    const int lane = tid & 63;
    const int lr   = lane & 15;
    const int quad = lane >> 4;
    const int wv   = tid >> 6;

    {
        const float4* xg = (const float4*)(x + (size_t)n0 * 128);
#pragma unroll
        for (int i = 0; i < 8; ++i) {
            int f = tid + 256 * i;
            float4 v = xg[f];
            int r = f >> 5, c = (f & 31) * 4;
            us4 p;
            p.x = f2bf(v.x); p.y = f2bf(v.y); p.z = f2bf(v.z); p.w = f2bf(v.w);
            *(us4*)&xbf[r][c] = p;
        }
    }
    __syncthreads();

    short8 af[4][4];
#pragma unroll
    for (int m = 0; m < 4; ++m)
#pragma unroll
        for (int kt = 0; kt < 4; ++kt)
            af[m][kt] = *(const short8*)&xbf[m * 16 + lr][kt * 32 + quad * 8];

    floatx4 acc[4][4];
#pragma unroll
    for (int n = 0; n < 4; ++n)
#pragma unroll
        for (int m = 0; m < 4; ++m)
            acc[n][m] = (floatx4){0.f, 0.f, 0.f, 0.f};

    const int nbase = wv * 64;
#pragma unroll
    for (int n = 0; n < 4; ++n) {
        const unsigned short* bp = &W1T[(size_t)(nbase + n * 16 + lr) * 128 + quad * 8];
        short8 bfr[4];
#pragma unroll
        for (int kt = 0; kt < 4; ++kt) bfr[kt] = *(const short8*)(bp + kt * 32);
#pragma unroll
        for (int kt = 0; kt < 4; ++kt)
#pragma unroll
            for (int m = 0; m < 4; ++m)
                acc[n][m] = __builtin_amdgcn_mfma_f32_16x16x32_bf16(
                    af[m][kt], bfr[kt], acc[n][m], 0, 0, 0);
    }

#pragma unroll
    for (int n = 0; n < 4; ++n) {
        float bc = b1[nbase + n * 16 + lr];
#pragma unroll
        for (int m = 0; m < 4; ++m)
#pragma unroll
            for (int reg = 0; reg < 4; ++reg) {
                float v = lrelu(acc[n][m][reg] + bc);
                h1s[m * 16 + quad * 4 + reg][nbase + n * 16 + lr] = f2bf(v);
            }
    }
    __syncthreads();

    floatx4 acc2 = (floatx4){0.f, 0.f, 0.f, 0.f};
#pragma unroll
    for (int kt = 0; kt < 8; ++kt) {
        short8 a2 = *(const short8*)&h1s[wv * 16 + lr][kt * 32 + quad * 8];
        short8 b2f = *(const short8*)&W2T[lr * 256 + kt * 32 + quad * 8];
        acc2 = __builtin_amdgcn_mfma_f32_16x16x32_bf16(a2, b2f, acc2, 0, 0, 0);
    }
    float bb = b2[lr];
#pragma unroll
    for (int reg = 0; reg < 4; ++reg) {
        int r = n0 + wv * 16 + quad * 4 + reg;
        h[(size_t)r * 16 + lr] = lrelu(acc2[reg] + bb);
    }
}

// ---------------------------------------------------------------------------
// K0: zero the global bucket counters
// ---------------------------------------------------------------------------
__global__ void zero_kernel(int* __restrict__ bcnt)
{
    bcnt[threadIdx.x] = 0;
}

// ---------------------------------------------------------------------------
// K2: per-bucket edge histogram (LDS-aggregated)
// ---------------------------------------------------------------------------
__global__ __launch_bounds__(256) void bucket_count(
    const int* __restrict__ eidx, int* __restrict__ bcnt, int E, int N, int B)
{
    __shared__ int hist[BMAX];
    const int t = threadIdx.x;
    for (int b = t; b < B; b += 256) hist[b] = 0;
    __syncthreads();

    const int stride = gridDim.x * 256;
    for (int e = blockIdx.x * 256 + t; e < E; e += stride) {
        int d = eidx[E + e];
        d = min(max(d, 0), N - 1);
        atomicAdd(&hist[d >> SHIFT], 1);
    }
    __syncthreads();
    for (int b = t; b < B; b += 256) {
        int c = hist[b];
        if (c) atomicAdd(&bcnt[b], c);
    }
}

// ---------------------------------------------------------------------------
// K3: single-block exclusive scan over bucket counts
// ---------------------------------------------------------------------------
__global__ __launch_bounds__(512) void scan_kernel(
    const int* __restrict__ bcnt, int* __restrict__ bbase, int* __restrict__ gcur, int B)
{
    __shared__ int s[BMAX];
    const int t = threadIdx.x;        // 512 threads
    int c = (t < B) ? bcnt[t] : 0;
    s[t] = c;
    __syncthreads();
#pragma unroll
    for (int off = 1; off < BMAX; off <<= 1) {
        int v = s[t];
        int u = (t >= off) ? s[t - off] : 0;
        __syncthreads();
        s[t] = v + u;
        __syncthreads();
    }
    if (t < B) {
        int excl = s[t] - c;
        bbase[t] = excl;
        gcur[t]  = excl;
    }
    if (t == 0) bbase[B] = s[BMAX - 1];
}

// ---------------------------------------------------------------------------
// K4: partition via block-level LDS counting sort + coalesced run flush.
// ---------------------------------------------------------------------------
__global__ __launch_bounds__(512) void partition_kernel(
    const int* __restrict__ eidx, int* __restrict__ gcur, int* __restrict__ pairs,
    int E, int N, int B)
{
    __shared__ int hist[BMAX];        // count -> cursor
    __shared__ int offx[BMAX + 1];    // exclusive local offsets (kept intact)
    __shared__ int basec[BMAX];       // global run base for this block
    __shared__ int sorted[PCHUNK];    // 32KB; doubles as scan scratch
    const int t  = threadIdx.x;
    const int e0 = blockIdx.x * PCHUNK;
    const int elim = min(PCHUNK, E - e0);

    hist[t] = 0;
    __syncthreads();
    for (int i = t; i < elim; i += 512) {
        int d = eidx[E + e0 + i];
        d = min(max(d, 0), N - 1);
        atomicAdd(&hist[d >> SHIFT], 1);
    }
    __syncthreads();

    int c = hist[t];
    sorted[t] = c;
    __syncthreads();
#pragma unroll
    for (int o = 1; o < BMAX; o <<= 1) {
        int v = sorted[t];
        int u = (t >= o) ? sorted[t - o] : 0;
        __syncthreads();
        sorted[t] = v + u;
        __syncthreads();
    }
    const int excl = sorted[t] - c;
    offx[t] = excl;
    if (t == 0) offx[BMAX] = elim;
    basec[t] = (t < B && c) ? atomicAdd(&gcur[t], c) : 0;
    hist[t] = excl;                   // becomes local cursor
    __syncthreads();

    for (int i = t; i < elim; i += 512) {
        int s = eidx[e0 + i];
        int d = eidx[E + e0 + i];
        s = min(max(s, 0), N - 1);
        d = min(max(d, 0), N - 1);
        int b = d >> SHIFT;
        int p = atomicAdd(&hist[b], 1);
        sorted[p] = (s << SHIFT) | (d & (BNODES - 1));
    }
    __syncthreads();

    for (int slot = t; slot < elim; slot += 512) {
        int v = sorted[slot];
        int l = 0, r = BMAX - 1;
#pragma unroll
        for (int it = 0; it < 9; ++it) {
            int m = (l + r + 1) >> 1;
            if (offx[m] <= slot) l = m; else r = m - 1;
        }
        pairs[basec[l] + (slot - offx[l])] = v;
    }
}

// ---------------------------------------------------------------------------
// K5: per-bucket counting sort -> csr, plus row_start/cnt/dinv
// ---------------------------------------------------------------------------
__global__ __launch_bounds__(512) void build_csr(
    const int* __restrict__ pairs, const int* __restrict__ bbase,
    int* __restrict__ row_start, int* __restrict__ cnt_out, float* __restrict__ dinv,
    int* __restrict__ csr, int N)
{
    __shared__ int cnt[BNODES];
    __shared__ int off[BNODES];
    const int b = blockIdx.x, t = threadIdx.x;   // 512 threads
    const int node0 = b << SHIFT;
    const int lo = bbase[b], hi = bbase[b + 1];

    cnt[t] = 0;
    __syncthreads();
    for (int e = lo + t; e < hi; e += 512)
        atomicAdd(&cnt[pairs[e] & (BNODES - 1)], 1);
    __syncthreads();

    int c = cnt[t];
    off[t] = c;
    __syncthreads();
#pragma unroll
    for (int o = 1; o < BNODES; o <<= 1) {
        int v = off[t];
        int u = (t >= o) ? off[t - o] : 0;
        __syncthreads();
        off[t] = v + u;
        __syncthreads();
    }
    const int excl = off[t] - c;
    const int node = node0 + t;
    if (node < N) {
        row_start[node] = lo + excl;
        cnt_out[node]   = c;
        dinv[node]      = rsqrtf((float)(c + 1));
    }
    cnt[t] = lo + excl;              // reuse as cursor
    __syncthreads();
    for (int e = lo + t; e < hi; e += 512) {
        int v = pairs[e];
        int p = atomicAdd(&cnt[v & (BNODES - 1)], 1);
        csr[p] = v >> SHIFT;
    }
}

// ---------------------------------------------------------------------------
// K6: hw = (optionally lrelu(in + bias_prev)) @ W[16x16] -> bf16 rows (32B).
// ---------------------------------------------------------------------------
__global__ void hw_kernel(const float* __restrict__ in, const float* __restrict__ W,
                          const float* __restrict__ bias, unsigned short* __restrict__ out,
                          int N, int apply)
{
    int i = blockIdx.x * 256 + threadIdx.x;
    if (i >= N) return;
    const float4* ir = (const float4*)(in + (size_t)i * 16);
    float4 r0 = ir[0], r1 = ir[1], r2 = ir[2], r3 = ir[3];
    float v[16] = {r0.x, r0.y, r0.z, r0.w, r1.x, r1.y, r1.z, r1.w,
                   r2.x, r2.y, r2.z, r2.w, r3.x, r3.y, r3.z, r3.w};
    if (apply) {
#pragma unroll
        for (int c = 0; c < 16; ++c) v[c] = lrelu(v[c] + bias[c]);
    }
    float o[16];
#pragma unroll
    for (int c = 0; c < 16; ++c) o[c] = 0.0f;
#pragma unroll
    for (int k = 0; k < 16; ++k) {
        float vk = v[k];
#pragma unroll
        for (int c = 0; c < 16; ++c) o[c] += vk * W[k * 16 + c];
    }
    us8 lo, hi;
#pragma unroll
    for (int c = 0; c < 8; ++c) { lo[c] = f2bf(o[c]); hi[c] = f2bf(o[c + 8]); }
    us8* orow = (us8*)(out + (size_t)i * 16);
    orow[0] = lo;
    orow[1] = hi;
}

// ---------------------------------------------------------------------------
// K7: gather conv over bf16 rows. 8 lanes/node, lane cp owns features 2cp,2cp+1.
// agg[d] = dinv_d * (hw_d*dinv_d + sum_src hw_src*dinv_src)
// ---------------------------------------------------------------------------
__global__ __launch_bounds__(256) void gather_kernel(
    const unsigned short* __restrict__ hws, const float* __restrict__ dinv,
    const int* __restrict__ csr, const int* __restrict__ row_start,
    const int* __restrict__ cnt, float* __restrict__ agg, int N)
{
    int t    = blockIdx.x * 256 + threadIdx.x;
    int node = t >> 3;
    int cp   = t & 7;
    if (node >= N) return;

    const unsigned int* rows = (const unsigned int*)hws;   // row i = 8 uints

    int   s0 = row_start[node];
    int   n  = cnt[node];
    float di = dinv[node];
    unsigned int self = rows[(size_t)node * 8 + cp];
    float a0 = bflo(self) * di, a1 = bfhi(self) * di;

    int j = 0;
    for (; j + 4 <= n; j += 4) {
        int sa = csr[s0 + j + 0]; int sb = csr[s0 + j + 1];
        int sc = csr[s0 + j + 2]; int sd = csr[s0 + j + 3];
        unsigned int va = rows[(size_t)sa * 8 + cp];
        unsigned int vb = rows[(size_t)sb * 8 + cp];
        unsigned int vc = rows[(size_t)sc * 8 + cp];
        unsigned int vd = rows[(size_t)sd * 8 + cp];
        float da = dinv[sa], db = dinv[sb], dc = dinv[sc], dd = dinv[sd];
        a0 += bflo(va) * da; a1 += bfhi(va) * da;
        a0 += bflo(vb) * db; a1 += bfhi(vb) * db;
        a0 += bflo(vc) * dc; a1 += bfhi(vc) * dc;
        a0 += bflo(vd) * dd; a1 += bfhi(vd) * dd;
    }
    for (; j < n; ++j) {
        int s = csr[s0 + j];
        unsigned int v = rows[(size_t)s * 8 + cp];
        float ds = dinv[s];
        a0 += bflo(v) * ds; a1 += bfhi(v) * ds;
    }
    *(float2*)&agg[(size_t)node * 16 + cp * 2] = make_float2(a0 * di, a1 * di);
}

// ---------------------------------------------------------------------------
// K8: final head. h = lrelu(agg + cb1); out = h . (pw[:,0]+pw[:,1]) + pb0+pb1
// ---------------------------------------------------------------------------
__global__ void final_kernel(const float* __restrict__ agg, const float* __restrict__ cb1,
                             const float* __restrict__ pw, const float* __restrict__ pb,
                             float* __restrict__ out, float* __restrict__ hout, int N)
{
    int i = blockIdx.x * 256 + threadIdx.x;
    if (i >= N) return;
    const float4* ar = (const float4*)(agg + (size_t)i * 16);
    float4 r0 = ar[0], r1 = ar[1], r2 = ar[2], r3 = ar[3];
    float v[16] = {r0.x, r0.y, r0.z, r0.w, r1.x, r1.y, r1.z, r1.w,
                   r2.x, r2.y, r2.z, r2.w, r3.x, r3.y, r3.z, r3.w};
    float s = pb[0] + pb[1];
#pragma unroll
    for (int c = 0; c < 16; ++c) {
        v[c] = lrelu(v[c] + cb1[c]);
        s += v[c] * (pw[c * 2] + pw[c * 2 + 1]);
    }
    out[i] = s;
    float4* hr = (float4*)(hout + (size_t)i * 16);
    hr[0] = make_float4(v[0],  v[1],  v[2],  v[3]);
    hr[1] = make_float4(v[4],  v[5],  v[6],  v[7]);
    hr[2] = make_float4(v[8],  v[9],  v[10], v[11]);
    hr[3] = make_float4(v[12], v[13], v[14], v[15]);
}

// ---------------------------------------------------------------------------
extern "C" void kernel_launch(void* const* d_in, const int* in_sizes, int n_in,
                              void* d_out, int out_size, void* d_ws, size_t ws_size,
                              hipStream_t stream)
{
    const float* x   = (const float*)d_in[0];
    const float* W1  = (const float*)d_in[1];
    const float* b1  = (const float*)d_in[2];
    const float* W2  = (const float*)d_in[3];
    const float* b2  = (const float*)d_in[4];
    const float* cw0 = (const float*)d_in[5];
    const float* cb0 = (const float*)d_in[6];
    const float* cw1 = (const float*)d_in[7];
    const float* cb1 = (const float*)d_in[8];
    const float* pw  = (const float*)d_in[9];
    const float* pb  = (const float*)d_in[10];
    const int*   eidx = (const int*)d_in[11];

    const int N = in_sizes[0] / 128;
    const int E = in_sizes[11] / 2;
    const int B = (N + BNODES - 1) >> SHIFT;

    // workspace carve-out (~60 MB); X region serves h -> pairs -> agg
    char* w = (char*)d_ws;
    unsigned short* hws = (unsigned short*)w; w += (size_t)N * 16 * 2;  // bf16 rows
    float* dinv    = (float*)w; w += (size_t)N * 4;
    int*   cnt     = (int*)w;   w += (size_t)N * 4;
    int*   row_st  = (int*)w;   w += (size_t)N * 4;
    int*   csr     = (int*)w;   w += (size_t)E * 4;
    char*  X       = w;         w += (size_t)E * 4;
    int*   bcnt    = (int*)w;   w += BMAX * 4;
    int*   bbase   = (int*)w;   w += (BMAX + 4) * 4;   // +4 keeps 16B alignment below
    int*   gcur    = (int*)w;   w += BMAX * 4;
    unsigned short* W1T = (unsigned short*)w; w += 256 * 128 * 2;  // 16B-aligned
    unsigned short* W2T = (unsigned short*)w; w += 16 * 256 * 2;

    float* h     = (float*)X;   // live: mlp -> hw1
    int*   pairs = (int*)X;     // live: partition -> build_csr
    float* agg   = (float*)X;   // live: gather1 -> final

    float* out  = (float*)d_out;
    float* hout = out + N;

    const int nb_n = (N + 255) / 256;
    const int nb_g = (N * 8 + 255) / 256;
    const int nb_p = (E + PCHUNK - 1) / PCHUNK;

    zero_kernel<<<1, BMAX, 0, stream>>>(bcnt);
    bucket_count<<<1024, 256, 0, stream>>>(eidx, bcnt, E, N, B);
    scan_kernel<<<1, BMAX, 0, stream>>>(bcnt, bbase, gcur, B);
    prep_kernel<<<32, 256, 0, stream>>>(W1, W2, W1T, W2T);
    mlp_mfma<<<N / 64, 256, 0, stream>>>(x, W1T, b1, W2T, b2, h, N);
    hw_kernel<<<nb_n, 256, 0, stream>>>(h, cw0, nullptr, hws, N, 0);   // h dead after this
    partition_kernel<<<nb_p, 512, 0, stream>>>(eidx, gcur, pairs, E, N, B);
    build_csr<<<B, 512, 0, stream>>>(pairs, bbase, row_st, cnt, dinv, csr, N);
    gather_kernel<<<nb_g, 256, 0, stream>>>(hws, dinv, csr, row_st, cnt, agg, N); // pairs dead
    hw_kernel<<<nb_n, 256, 0, stream>>>(agg, cw1, cb0, hws, N, 1);
    gather_kernel<<<nb_g, 256, 0, stream>>>(hws, dinv, csr, row_st, cnt, agg, N);
    final_kernel<<<nb_n, 256, 0, stream>>>(agg, cb1, pw, pb, out, hout, N);
}